// Round 1
// baseline (1023.605 us; speedup 1.0000x reference)
//
#include <hip/hip_runtime.h>
#include <math.h>

#define N_NODES 50000
#define N_EDGES 1000000
#define DIM 64
#define CAP 64
#define LN_EPS 1e-5f

// ---------------------------------------------------------------- wave utils
__device__ __forceinline__ float wave_sum(float v) {
#pragma unroll
  for (int off = 32; off >= 1; off >>= 1) v += __shfl_xor(v, off, 64);
  return v;
}

// ---------------------------------------------------------------- ELL build
__global__ __launch_bounds__(256) void build_ell(const int* __restrict__ ei,
                                                 int* __restrict__ cursor,
                                                 int* __restrict__ ell) {
  int e = blockIdx.x * 256 + threadIdx.x;
  if (e >= N_EDGES) return;
  int src = ei[e];             // edge_index[0][e]
  int dst = ei[N_EDGES + e];   // edge_index[1][e]
  int pos = atomicAdd(&cursor[dst], 1);
  if (pos < CAP) ell[dst * CAP + pos] = src;
}

// ---------------------------------------------------------------- fused QKVS GEMM
// out[n][0:64)=Q, [64:128)=K, [128:192)=V, [192:256)=S   (S = h@Ws + bs)
__global__ __launch_bounds__(256) void gemm_qkvs(
    const float* __restrict__ h,
    const float* __restrict__ Wq, const float* __restrict__ bq,
    const float* __restrict__ Wk, const float* __restrict__ bk,
    const float* __restrict__ Wv, const float* __restrict__ bv,
    const float* __restrict__ Ws, const float* __restrict__ bs,
    float* __restrict__ out) {
  int row = blockIdx.x * 256 + threadIdx.x;
  if (row >= N_NODES) return;

  float hr[64];
  const float4* h4 = reinterpret_cast<const float4*>(h + (size_t)row * 64);
#pragma unroll
  for (int i = 0; i < 16; ++i) {
    float4 t = h4[i];
    hr[4 * i + 0] = t.x; hr[4 * i + 1] = t.y;
    hr[4 * i + 2] = t.z; hr[4 * i + 3] = t.w;
  }

  const float* Wm[4] = {Wq, Wk, Wv, Ws};
  const float* Bm[4] = {bq, bk, bv, bs};
  float* orow = out + (size_t)row * 256;

#pragma unroll
  for (int mIdx = 0; mIdx < 4; ++mIdx) {
    const float* __restrict__ W = Wm[mIdx];
    const float* __restrict__ B = Bm[mIdx];
    for (int c = 0; c < 64; c += 4) {  // dynamic: keeps code size sane
      float a0 = B[c + 0], a1 = B[c + 1], a2 = B[c + 2], a3 = B[c + 3];
#pragma unroll
      for (int k = 0; k < 64; ++k) {
        float hk = hr[k];
        const float* wrow = W + k * 64 + c;  // wave-uniform -> s_load
        a0 = fmaf(hk, wrow[0], a0);
        a1 = fmaf(hk, wrow[1], a1);
        a2 = fmaf(hk, wrow[2], a2);
        a3 = fmaf(hk, wrow[3], a3);
      }
      float4 r = {a0, a1, a2, a3};
      *reinterpret_cast<float4*>(orow + mIdx * 64 + c) = r;
    }
  }
}

// ---------------------------------------------------------------- edge + softmax + LN + relu
// one wave per dst node; lane = feature dim
__global__ __launch_bounds__(256) void edge_softmax_ln(
    const float* __restrict__ qkvs,
    const int* __restrict__ ell, const int* __restrict__ cursor,
    const float* __restrict__ ln_g, const float* __restrict__ ln_b,
    const float* __restrict__ h_res, float* __restrict__ h_out,
    int use_res) {
  int node = blockIdx.x * 4 + (threadIdx.x >> 6);
  if (node >= N_NODES) return;
  int lane = threadIdx.x & 63;

  int deg = cursor[node];
  if (deg > CAP) deg = CAP;
  const int* lst = ell + (size_t)node * CAP;

  float q = qkvs[(size_t)node * 256 + lane];
  float m = -INFINITY, s = 0.f, acc = 0.f;

  for (int e = 0; e < deg; ++e) {
    int src = lst[e];  // wave-uniform scalar load
    const float* base = qkvs + (size_t)src * 256;
    float kv = base[64 + lane];
    float dotp = wave_sum(q * kv) * 0.125f;  // /sqrt(64)
    float mn = fmaxf(m, dotp);
    float sc = __expf(m - mn);   // m=-inf first iter -> 0
    float w  = __expf(dotp - mn);
    float vv = base[128 + lane];
    s   = s * sc + w;
    acc = acc * sc + w * vv;
    m = mn;
  }

  float agg = (s > 0.f) ? (acc / s) : 0.f;
  float out = agg + qkvs[(size_t)node * 256 + 192 + lane];  // skip: h@Ws+bs
  if (use_res) out += h_res[(size_t)node * 64 + lane];

  // LayerNorm over 64 dims (= 64 lanes) + ReLU
  float mu = wave_sum(out) * (1.f / 64.f);
  float d = out - mu;
  float var = wave_sum(d * d) * (1.f / 64.f);
  float y = d * rsqrtf(var + LN_EPS) * ln_g[lane] + ln_b[lane];
  h_out[(size_t)node * 64 + lane] = fmaxf(y, 0.f);
}

// ---------------------------------------------------------------- launch
extern "C" void kernel_launch(void* const* d_in, const int* in_sizes, int n_in,
                              void* d_out, int out_size, void* d_ws, size_t ws_size,
                              hipStream_t stream) {
  const float* x    = (const float*)d_in[0];
  const int*   ei   = (const int*)d_in[1];
  const float* Wq0  = (const float*)d_in[2];
  const float* bq0  = (const float*)d_in[3];
  const float* Wk0  = (const float*)d_in[4];
  const float* bk0  = (const float*)d_in[5];
  const float* Wv0  = (const float*)d_in[6];
  const float* bv0  = (const float*)d_in[7];
  const float* Ws0  = (const float*)d_in[8];
  const float* bs0  = (const float*)d_in[9];
  const float* ln0g = (const float*)d_in[10];
  const float* ln0b = (const float*)d_in[11];
  const float* WqL  = (const float*)d_in[12];
  const float* bqL  = (const float*)d_in[13];
  const float* WkL  = (const float*)d_in[14];
  const float* bkL  = (const float*)d_in[15];
  const float* WvL  = (const float*)d_in[16];
  const float* bvL  = (const float*)d_in[17];
  const float* WsL  = (const float*)d_in[18];
  const float* bsL  = (const float*)d_in[19];
  const float* lnG  = (const float*)d_in[20];
  const float* lnB  = (const float*)d_in[21];

  float* h = (float*)d_out;  // [N,64] — used as the running hidden state

  char* ws = (char*)d_ws;
  float* qkvs  = (float*)ws;                                   // N*256 f32 (51.2MB)
  int*   ell   = (int*)(ws + (size_t)N_NODES * 256 * 4);       // N*CAP   (12.8MB)
  int*   cursor= (int*)(ws + (size_t)N_NODES * 256 * 4
                           + (size_t)N_NODES * CAP * 4);       // N

  hipMemsetAsync(cursor, 0, N_NODES * sizeof(int), stream);
  build_ell<<<(N_EDGES + 255) / 256, 256, 0, stream>>>(ei, cursor, ell);

  for (int layer = 0; layer < 4; ++layer) {
    const float* hin = (layer == 0) ? x : h;
    const float *wq, *bq, *wk, *bk, *wv, *bv, *wsm, *bs, *lg, *lb;
    if (layer == 0) {
      wq = Wq0; bq = bq0; wk = Wk0; bk = bk0;
      wv = Wv0; bv = bv0; wsm = Ws0; bs = bs0;
      lg = ln0g; lb = ln0b;
    } else {
      int i = layer - 1;
      wq = WqL + (size_t)i * 64 * 64; bq = bqL + (size_t)i * 64;
      wk = WkL + (size_t)i * 64 * 64; bk = bkL + (size_t)i * 64;
      wv = WvL + (size_t)i * 64 * 64; bv = bvL + (size_t)i * 64;
      wsm = WsL + (size_t)i * 64 * 64; bs = bsL + (size_t)i * 64;
      lg = lnG + (size_t)i * 64; lb = lnB + (size_t)i * 64;
    }
    gemm_qkvs<<<(N_NODES + 255) / 256, 256, 0, stream>>>(
        hin, wq, bq, wk, bk, wv, bv, wsm, bs, qkvs);
    edge_softmax_ln<<<(N_NODES + 3) / 4, 256, 0, stream>>>(
        qkvs, ell, cursor, lg, lb, h, h, layer > 0 ? 1 : 0);
  }
}

// Round 2
// 436.236 us; speedup vs baseline: 2.3464x; 2.3464x over previous
//
#include <hip/hip_runtime.h>
#include <math.h>

#define NN 50000
#define NE 1000000
#define CAP 64
#define LN_EPS 1e-5f
#define ROW_TILES 3125  // 50000 / 16

typedef __attribute__((ext_vector_type(8))) short short8;
typedef __attribute__((ext_vector_type(4))) float f32x4;

__device__ __forceinline__ unsigned short f2bf(float f) {
  union { float f; unsigned u; } v; v.f = f;
  unsigned r = v.u + 0x7FFF + ((v.u >> 16) & 1);  // RNE
  return (unsigned short)(r >> 16);
}
__device__ __forceinline__ float bf2f(unsigned short b) {
  union { unsigned u; float f; } v; v.u = ((unsigned)b) << 16;
  return v.f;
}

// ---------------------------------------------------------------- ELL build
__global__ __launch_bounds__(256) void build_ell(const int* __restrict__ ei,
                                                 int* __restrict__ cursor,
                                                 int* __restrict__ ell) {
  int e = blockIdx.x * 256 + threadIdx.x;
  if (e >= NE) return;
  int src = ei[e];
  int dst = ei[NE + e];
  int pos = atomicAdd(&cursor[dst], 1);
  if (pos < CAP) ell[(size_t)dst * CAP + pos] = src;
}

// ---------------------------------------------------------------- weight prep
// Wt per layer: [256][64] bf16, row c = mat*64 + n, holds W[k][n] (transposed).
// Bc per layer: [256] f32 concat biases.
__global__ __launch_bounds__(256) void wprep(
    const float* __restrict__ Wq0, const float* __restrict__ bq0,
    const float* __restrict__ Wk0, const float* __restrict__ bk0,
    const float* __restrict__ Wv0, const float* __restrict__ bv0,
    const float* __restrict__ Ws0, const float* __restrict__ bs0,
    const float* __restrict__ WqL, const float* __restrict__ bqL,
    const float* __restrict__ WkL, const float* __restrict__ bkL,
    const float* __restrict__ WvL, const float* __restrict__ bvL,
    const float* __restrict__ WsL, const float* __restrict__ bsL,
    unsigned short* __restrict__ Wt, float* __restrict__ Bc) {
  int tid = blockIdx.x * 256 + threadIdx.x;
  if (tid >= 4 * 256 * 64) return;
  int lyr = tid >> 14;
  int rem = tid & 16383;
  int c = rem >> 6;   // 0..255
  int k = rem & 63;
  int m = c >> 6;
  int n = c & 63;
  const float *W, *B;
  if (lyr == 0) {
    const float* Wm[4] = {Wq0, Wk0, Wv0, Ws0};
    const float* Bm[4] = {bq0, bk0, bv0, bs0};
    W = Wm[m]; B = Bm[m];
  } else {
    const float* Wm[4] = {WqL, WkL, WvL, WsL};
    const float* Bm[4] = {bqL, bkL, bvL, bsL};
    W = Wm[m] + (size_t)(lyr - 1) * 4096;
    B = Bm[m] + (size_t)(lyr - 1) * 64;
  }
  Wt[(size_t)lyr * 16384 + (size_t)c * 64 + k] = f2bf(W[(size_t)k * 64 + n]);
  if (k == 0) Bc[lyr * 256 + c] = B[n];
}

// ---------------------------------------------------------------- MFMA QKVS GEMM
// h [N,64] f32 -> Qf f32, Kb bf16, Vb bf16, Sf f32 (each [N,64])
__global__ __launch_bounds__(256) void gemm_qkvs(
    const float* __restrict__ h, const unsigned short* __restrict__ Wt,
    const float* __restrict__ Bc, float* __restrict__ Qf,
    unsigned short* __restrict__ Kb, unsigned short* __restrict__ Vb,
    float* __restrict__ Sf) {
  __shared__ unsigned short lw[256 * 72];  // padded stride 72 (144B) vs 64
  int tid = threadIdx.x;
#pragma unroll
  for (int it = 0; it < 8; ++it) {
    int id = it * 256 + tid;          // 2048 chunks of 16B
    int row = id >> 3, cc = id & 7;
    float4 src = *reinterpret_cast<const float4*>(Wt + (size_t)row * 64 + cc * 8);
    *reinterpret_cast<float4*>(lw + (size_t)row * 72 + cc * 8) = src;
  }
  __syncthreads();

  int wave = tid >> 6, lane = tid & 63;
  int tile = blockIdx.x * 4 + wave;
  if (tile >= ROW_TILES) return;
  int lo = lane & 15, hi = lane >> 4;
  int row = tile * 16 + lo;
  const float* hrow = h + (size_t)row * 64;

  auto packA = [&](const float* p) {
    float4 x = *reinterpret_cast<const float4*>(p);
    float4 y = *reinterpret_cast<const float4*>(p + 4);
    short8 r;
    r[0] = (short)f2bf(x.x); r[1] = (short)f2bf(x.y);
    r[2] = (short)f2bf(x.z); r[3] = (short)f2bf(x.w);
    r[4] = (short)f2bf(y.x); r[5] = (short)f2bf(y.y);
    r[6] = (short)f2bf(y.z); r[7] = (short)f2bf(y.w);
    return r;
  };
  short8 a0 = packA(hrow + hi * 8);        // k = hi*8 .. +7
  short8 a1 = packA(hrow + 32 + hi * 8);   // k = 32 + hi*8 .. +7

#pragma unroll
  for (int ct = 0; ct < 16; ++ct) {
    float bias = Bc[ct * 16 + lo];
    f32x4 acc = {bias, bias, bias, bias};  // lane's 4 rows share one column
    const unsigned short* wr = lw + (size_t)(ct * 16 + lo) * 72 + hi * 8;
    short8 b0 = *reinterpret_cast<const short8*>(wr);
    short8 b1 = *reinterpret_cast<const short8*>(wr + 32);
    acc = __builtin_amdgcn_mfma_f32_16x16x32_bf16(a0, b0, acc, 0, 0, 0);
    acc = __builtin_amdgcn_mfma_f32_16x16x32_bf16(a1, b1, acc, 0, 0, 0);
    int mat = ct >> 2;
    int col = (ct & 3) * 16 + lo;
    int rb = tile * 16 + hi * 4;
#pragma unroll
    for (int r = 0; r < 4; ++r) {
      float val = acc[r];
      size_t off = (size_t)(rb + r) * 64 + col;
      if (mat == 0) Qf[off] = val;
      else if (mat == 1) Kb[off] = f2bf(val);
      else if (mat == 2) Vb[off] = f2bf(val);
      else Sf[off] = val;
    }
  }
}

// ---------------------------------------------------------------- fused edge+softmax+LN+relu
// one wave per node; lane = (g = edge slot 0..3) x (t = dim quarter 0..15)
__global__ __launch_bounds__(256) void edge_fused(
    const float* __restrict__ Qf, const unsigned short* __restrict__ Kb,
    const unsigned short* __restrict__ Vb, const float* __restrict__ Sf,
    const int* __restrict__ ell, const int* __restrict__ cursor,
    const float* __restrict__ ln_g, const float* __restrict__ ln_b,
    const float* __restrict__ h_res, float* __restrict__ h_out, int use_res) {
  int node = blockIdx.x * 4 + (threadIdx.x >> 6);
  if (node >= NN) return;
  int lane = threadIdx.x & 63;
  int g = lane >> 4, t = lane & 15;

  int deg = cursor[node];
  if (deg > CAP) deg = CAP;
  const int* lst = ell + (size_t)node * CAP;

  float4 q4 = *reinterpret_cast<const float4*>(Qf + (size_t)node * 64 + t * 4);

  float4 acc = {0.f, 0.f, 0.f, 0.f};
  float ssum = 0.f;
  int passes = (deg + 3) >> 2;
  for (int p = 0; p < passes; ++p) {
    int slot = p * 4 + g;
    bool valid = slot < deg;
    int src = valid ? lst[slot] : 0;
    ushort4 kk = *reinterpret_cast<const ushort4*>(Kb + (size_t)src * 64 + t * 4);
    ushort4 vv = *reinterpret_cast<const ushort4*>(Vb + (size_t)src * 64 + t * 4);
    float dp = q4.x * bf2f(kk.x) + q4.y * bf2f(kk.y) +
               q4.z * bf2f(kk.z) + q4.w * bf2f(kk.w);
    dp += __shfl_xor(dp, 1, 64);
    dp += __shfl_xor(dp, 2, 64);
    dp += __shfl_xor(dp, 4, 64);
    dp += __shfl_xor(dp, 8, 64);
    // softmax is shift-invariant; logits here are O(1) -> no max subtraction
    float w = valid ? __expf(dp * 0.125f) : 0.f;
    ssum += w;
    acc.x = fmaf(w, bf2f(vv.x), acc.x);
    acc.y = fmaf(w, bf2f(vv.y), acc.y);
    acc.z = fmaf(w, bf2f(vv.z), acc.z);
    acc.w = fmaf(w, bf2f(vv.w), acc.w);
  }
  // combine the 4 edge groups
#pragma unroll
  for (int off = 16; off <= 32; off <<= 1) {
    acc.x += __shfl_xor(acc.x, off, 64);
    acc.y += __shfl_xor(acc.y, off, 64);
    acc.z += __shfl_xor(acc.z, off, 64);
    acc.w += __shfl_xor(acc.w, off, 64);
    ssum  += __shfl_xor(ssum, off, 64);
  }
  float inv = (ssum > 0.f) ? (1.f / ssum) : 0.f;

  float4 s4 = *reinterpret_cast<const float4*>(Sf + (size_t)node * 64 + t * 4);
  float4 o;
  o.x = acc.x * inv + s4.x;
  o.y = acc.y * inv + s4.y;
  o.z = acc.z * inv + s4.z;
  o.w = acc.w * inv + s4.w;
  if (use_res) {
    float4 r4 = *reinterpret_cast<const float4*>(h_res + (size_t)node * 64 + t * 4);
    o.x += r4.x; o.y += r4.y; o.z += r4.z; o.w += r4.w;
  }

  // LayerNorm over 64 dims (16 lanes x float4; groups hold identical copies)
  float sum = o.x + o.y + o.z + o.w;
  sum += __shfl_xor(sum, 1, 64);
  sum += __shfl_xor(sum, 2, 64);
  sum += __shfl_xor(sum, 4, 64);
  sum += __shfl_xor(sum, 8, 64);
  float mu = sum * (1.f / 64.f);
  float dx = o.x - mu, dy = o.y - mu, dz = o.z - mu, dw = o.w - mu;
  float vs = dx * dx + dy * dy + dz * dz + dw * dw;
  vs += __shfl_xor(vs, 1, 64);
  vs += __shfl_xor(vs, 2, 64);
  vs += __shfl_xor(vs, 4, 64);
  vs += __shfl_xor(vs, 8, 64);
  float rstd = rsqrtf(vs * (1.f / 64.f) + LN_EPS);
  float4 gg = *reinterpret_cast<const float4*>(ln_g + t * 4);
  float4 bb = *reinterpret_cast<const float4*>(ln_b + t * 4);
  float4 y;
  y.x = fmaxf(dx * rstd * gg.x + bb.x, 0.f);
  y.y = fmaxf(dy * rstd * gg.y + bb.y, 0.f);
  y.z = fmaxf(dz * rstd * gg.z + bb.z, 0.f);
  y.w = fmaxf(dw * rstd * gg.w + bb.w, 0.f);
  *reinterpret_cast<float4*>(h_out + (size_t)node * 64 + t * 4) = y;
}

// ---------------------------------------------------------------- launch
extern "C" void kernel_launch(void* const* d_in, const int* in_sizes, int n_in,
                              void* d_out, int out_size, void* d_ws, size_t ws_size,
                              hipStream_t stream) {
  const float* x    = (const float*)d_in[0];
  const int*   ei   = (const int*)d_in[1];
  const float* Wq0  = (const float*)d_in[2];
  const float* bq0  = (const float*)d_in[3];
  const float* Wk0  = (const float*)d_in[4];
  const float* bk0  = (const float*)d_in[5];
  const float* Wv0  = (const float*)d_in[6];
  const float* bv0  = (const float*)d_in[7];
  const float* Ws0  = (const float*)d_in[8];
  const float* bs0  = (const float*)d_in[9];
  const float* ln0g = (const float*)d_in[10];
  const float* ln0b = (const float*)d_in[11];
  const float* WqL  = (const float*)d_in[12];
  const float* bqL  = (const float*)d_in[13];
  const float* WkL  = (const float*)d_in[14];
  const float* bkL  = (const float*)d_in[15];
  const float* WvL  = (const float*)d_in[16];
  const float* bvL  = (const float*)d_in[17];
  const float* WsL  = (const float*)d_in[18];
  const float* bsL  = (const float*)d_in[19];
  const float* lnG  = (const float*)d_in[20];
  const float* lnB  = (const float*)d_in[21];

  float* h = (float*)d_out;  // running hidden state [N,64] f32

  char* ws = (char*)d_ws;
  size_t off = 0;
  float* Qf = (float*)(ws + off);           off += (size_t)NN * 64 * 4;   // 12.8MB
  float* Sf = (float*)(ws + off);           off += (size_t)NN * 64 * 4;   // 12.8MB
  unsigned short* Kb = (unsigned short*)(ws + off); off += (size_t)NN * 64 * 2; // 6.4MB
  unsigned short* Vb = (unsigned short*)(ws + off); off += (size_t)NN * 64 * 2; // 6.4MB
  int* ell = (int*)(ws + off);              off += (size_t)NN * CAP * 4;  // 12.8MB
  int* cursor = (int*)(ws + off);           off += (size_t)NN * 4;
  unsigned short* Wt = (unsigned short*)(ws + off); off += (size_t)4 * 256 * 64 * 2;
  float* Bc = (float*)(ws + off);           off += (size_t)4 * 256 * 4;

  hipMemsetAsync(cursor, 0, NN * sizeof(int), stream);
  build_ell<<<(NE + 255) / 256, 256, 0, stream>>>(ei, cursor, ell);
  wprep<<<256, 256, 0, stream>>>(Wq0, bq0, Wk0, bk0, Wv0, bv0, Ws0, bs0,
                                 WqL, bqL, WkL, bkL, WvL, bvL, WsL, bsL, Wt, Bc);

  for (int layer = 0; layer < 4; ++layer) {
    const float* hin = (layer == 0) ? x : h;
    const float* lg = (layer == 0) ? ln0g : lnG + (size_t)(layer - 1) * 64;
    const float* lb = (layer == 0) ? ln0b : lnB + (size_t)(layer - 1) * 64;
    gemm_qkvs<<<(ROW_TILES + 3) / 4, 256, 0, stream>>>(
        hin, Wt + (size_t)layer * 16384, Bc + (size_t)layer * 256, Qf, Kb, Vb, Sf);
    edge_fused<<<(NN + 3) / 4, 256, 0, stream>>>(
        Qf, Kb, Vb, Sf, ell, cursor, lg, lb, h, h, layer > 0 ? 1 : 0);
  }
}

// Round 4
// 423.734 us; speedup vs baseline: 2.4157x; 1.0295x over previous
//
#include <hip/hip_runtime.h>
#include <math.h>

#define NN 50000
#define NE 1000000
#define CAP 64
#define LN_EPS 1e-5f
#define ROW_TILES 3125   // 50000 / 16
#define BE_T 250112      // build_ell threads = 977 * 256 (x4 edges each)

typedef __attribute__((ext_vector_type(8))) short short8;
typedef __attribute__((ext_vector_type(8))) unsigned short ushort8;
typedef __attribute__((ext_vector_type(4))) float f32x4;

__device__ __forceinline__ unsigned short f2bf(float f) {
  union { float f; unsigned u; } v; v.f = f;
  unsigned r = v.u + 0x7FFF + ((v.u >> 16) & 1);  // RNE
  return (unsigned short)(r >> 16);
}
__device__ __forceinline__ float bf2f(unsigned short b) {
  union { unsigned u; float f; } v; v.u = ((unsigned)b) << 16;
  return v.f;
}

// ---------------------------------------------------------------- ELL build (ILP x4)
__global__ __launch_bounds__(256) void build_ell(const int* __restrict__ ei,
                                                 int* __restrict__ cursor,
                                                 unsigned short* __restrict__ ell) {
  int t = blockIdx.x * 256 + threadIdx.x;
  int e[4]; bool v[4]; int s[4], d[4], p[4];
#pragma unroll
  for (int i = 0; i < 4; ++i) { e[i] = t + i * BE_T; v[i] = e[i] < NE; }
#pragma unroll
  for (int i = 0; i < 4; ++i) {
    if (v[i]) { s[i] = ei[e[i]]; d[i] = ei[NE + e[i]]; }
  }
#pragma unroll
  for (int i = 0; i < 4; ++i) {
    if (v[i]) p[i] = atomicAdd(&cursor[d[i]], 1);
  }
#pragma unroll
  for (int i = 0; i < 4; ++i) {
    if (v[i] && p[i] < CAP) ell[(size_t)d[i] * CAP + p[i]] = (unsigned short)s[i];
  }
}

// ---------------------------------------------------------------- weight prep
// Wt per layer: [256][64] bf16, row c = mat*64 + n, holds W[k][n] (transposed).
__global__ __launch_bounds__(256) void wprep(
    const float* __restrict__ Wq0, const float* __restrict__ bq0,
    const float* __restrict__ Wk0, const float* __restrict__ bk0,
    const float* __restrict__ Wv0, const float* __restrict__ bv0,
    const float* __restrict__ Ws0, const float* __restrict__ bs0,
    const float* __restrict__ WqL, const float* __restrict__ bqL,
    const float* __restrict__ WkL, const float* __restrict__ bkL,
    const float* __restrict__ WvL, const float* __restrict__ bvL,
    const float* __restrict__ WsL, const float* __restrict__ bsL,
    unsigned short* __restrict__ Wt, float* __restrict__ Bc) {
  int tid = blockIdx.x * 256 + threadIdx.x;
  if (tid >= 4 * 256 * 64) return;
  int lyr = tid >> 14;
  int rem = tid & 16383;
  int c = rem >> 6;   // 0..255
  int k = rem & 63;
  int m = c >> 6;
  int n = c & 63;
  const float *W, *B;
  if (lyr == 0) {
    const float* Wm[4] = {Wq0, Wk0, Wv0, Ws0};
    const float* Bm[4] = {bq0, bk0, bv0, bs0};
    W = Wm[m]; B = Bm[m];
  } else {
    const float* Wm[4] = {WqL, WkL, WvL, WsL};
    const float* Bm[4] = {bqL, bkL, bvL, bsL};
    W = Wm[m] + (size_t)(lyr - 1) * 4096;
    B = Bm[m] + (size_t)(lyr - 1) * 64;
  }
  Wt[(size_t)lyr * 16384 + (size_t)c * 64 + k] = f2bf(W[(size_t)k * 64 + n]);
  if (k == 0) Bc[lyr * 256 + c] = B[n];
}

// ---------------------------------------------------------------- MFMA QKVS GEMM
// h [N,64] f32 -> Qf f32 [N,64], KVb bf16 interleaved [N,128] (k,v pairs), Sf f32
__global__ __launch_bounds__(256) void gemm_qkvs(
    const float* __restrict__ h, const unsigned short* __restrict__ Wt,
    const float* __restrict__ Bc, float* __restrict__ Qf,
    unsigned int* __restrict__ KVb, float* __restrict__ Sf) {
  __shared__ unsigned short lw[256 * 72];  // padded stride 72
  int tid = threadIdx.x;
#pragma unroll
  for (int it = 0; it < 8; ++it) {
    int id = it * 256 + tid;
    int row = id >> 3, cc = id & 7;
    float4 src = *reinterpret_cast<const float4*>(Wt + (size_t)row * 64 + cc * 8);
    *reinterpret_cast<float4*>(lw + (size_t)row * 72 + cc * 8) = src;
  }
  __syncthreads();

  int wave = tid >> 6, lane = tid & 63;
  int tile = blockIdx.x * 4 + wave;
  if (tile >= ROW_TILES) return;
  int lo = lane & 15, hi = lane >> 4;
  int row = tile * 16 + lo;
  const float* hrow = h + (size_t)row * 64;

  auto packA = [&](const float* p) {
    float4 x = *reinterpret_cast<const float4*>(p);
    float4 y = *reinterpret_cast<const float4*>(p + 4);
    short8 r;
    r[0] = (short)f2bf(x.x); r[1] = (short)f2bf(x.y);
    r[2] = (short)f2bf(x.z); r[3] = (short)f2bf(x.w);
    r[4] = (short)f2bf(y.x); r[5] = (short)f2bf(y.y);
    r[6] = (short)f2bf(y.z); r[7] = (short)f2bf(y.w);
    return r;
  };
  short8 a0 = packA(hrow + hi * 8);
  short8 a1 = packA(hrow + 32 + hi * 8);

  int rb = tile * 16 + hi * 4;

  auto mm = [&](int brow, float bias) {
    f32x4 acc = {bias, bias, bias, bias};
    const unsigned short* wr = lw + (size_t)brow * 72 + hi * 8;
    short8 b0 = *reinterpret_cast<const short8*>(wr);
    short8 b1 = *reinterpret_cast<const short8*>(wr + 32);
    acc = __builtin_amdgcn_mfma_f32_16x16x32_bf16(a0, b0, acc, 0, 0, 0);
    acc = __builtin_amdgcn_mfma_f32_16x16x32_bf16(a1, b1, acc, 0, 0, 0);
    return acc;
  };

  // Q (cols ct*16+lo), f32 out
#pragma unroll
  for (int ct = 0; ct < 4; ++ct) {
    int col = ct * 16 + lo;
    f32x4 acc = mm(col, Bc[col]);
#pragma unroll
    for (int r = 0; r < 4; ++r) Qf[(size_t)(rb + r) * 64 + col] = acc[r];
  }
  // K+V packed
#pragma unroll
  for (int cg = 0; cg < 4; ++cg) {
    int col = cg * 16 + lo;
    f32x4 aK = mm(64 + col, Bc[64 + col]);
    f32x4 aV = mm(128 + col, Bc[128 + col]);
#pragma unroll
    for (int r = 0; r < 4; ++r) {
      unsigned int pk = (unsigned int)f2bf(aK[r]) | ((unsigned int)f2bf(aV[r]) << 16);
      KVb[(size_t)(rb + r) * 64 + col] = pk;
    }
  }
  // S
#pragma unroll
  for (int ct = 0; ct < 4; ++ct) {
    int col = ct * 16 + lo;
    f32x4 acc = mm(192 + col, Bc[192 + col]);
#pragma unroll
    for (int r = 0; r < 4; ++r) Sf[(size_t)(rb + r) * 64 + col] = acc[r];
  }
}

// ---------------------------------------------------------------- fused edge+softmax+LN+relu
// one wave per node; lane = (g = edge slot 0..3) x (t = dim quarter 0..15)
__global__ __launch_bounds__(256) void edge_fused(
    const float* __restrict__ Qf, const unsigned short* __restrict__ KVb,
    const float* __restrict__ Sf,
    const unsigned short* __restrict__ ell, const int* __restrict__ cursor,
    const float* __restrict__ ln_g, const float* __restrict__ ln_b,
    const float* __restrict__ h_res, float* __restrict__ h_out, int use_res) {
  int node = blockIdx.x * 4 + (threadIdx.x >> 6);
  if (node >= NN) return;
  int lane = threadIdx.x & 63;
  int g = lane >> 4, t = lane & 15;

  int deg = cursor[node];
  if (deg > CAP) deg = CAP;
  const unsigned short* lst = ell + (size_t)node * CAP;

  float4 q4 = *reinterpret_cast<const float4*>(Qf + (size_t)node * 64 + t * 4);

  float4 acc = {0.f, 0.f, 0.f, 0.f};
  float ssum = 0.f;
  int passes = (deg + 3) >> 2;
  for (int p = 0; p < passes; ++p) {
    int slot = p * 4 + g;
    bool valid = slot < deg;
    int src = valid ? (int)lst[slot] : 0;
    // one 16B load: 4 (k,v) bf16 pairs for dims 4t..4t+3
    ushort8 kv = *reinterpret_cast<const ushort8*>(KVb + (size_t)src * 128 + t * 8);
    float dp = q4.x * bf2f(kv[0]) + q4.y * bf2f(kv[2]) +
               q4.z * bf2f(kv[4]) + q4.w * bf2f(kv[6]);
    dp += __shfl_xor(dp, 1, 64);
    dp += __shfl_xor(dp, 2, 64);
    dp += __shfl_xor(dp, 4, 64);
    dp += __shfl_xor(dp, 8, 64);
    // softmax is shift-invariant; logits O(1) -> no max subtraction needed
    float w = valid ? __expf(dp * 0.125f) : 0.f;
    ssum += w;
    acc.x = fmaf(w, bf2f(kv[1]), acc.x);
    acc.y = fmaf(w, bf2f(kv[3]), acc.y);
    acc.z = fmaf(w, bf2f(kv[5]), acc.z);
    acc.w = fmaf(w, bf2f(kv[7]), acc.w);
  }
  // combine the 4 edge groups
#pragma unroll
  for (int off = 16; off <= 32; off <<= 1) {
    acc.x += __shfl_xor(acc.x, off, 64);
    acc.y += __shfl_xor(acc.y, off, 64);
    acc.z += __shfl_xor(acc.z, off, 64);
    acc.w += __shfl_xor(acc.w, off, 64);
    ssum  += __shfl_xor(ssum, off, 64);
  }
  float inv = (ssum > 0.f) ? (1.f / ssum) : 0.f;

  float4 s4 = *reinterpret_cast<const float4*>(Sf + (size_t)node * 64 + t * 4);
  float4 o;
  o.x = acc.x * inv + s4.x;
  o.y = acc.y * inv + s4.y;
  o.z = acc.z * inv + s4.z;
  o.w = acc.w * inv + s4.w;
  if (use_res) {
    float4 r4 = *reinterpret_cast<const float4*>(h_res + (size_t)node * 64 + t * 4);
    o.x += r4.x; o.y += r4.y; o.z += r4.z; o.w += r4.w;
  }

  // LayerNorm over 64 dims (16 lanes x float4; groups hold identical copies)
  float sum = o.x + o.y + o.z + o.w;
  sum += __shfl_xor(sum, 1, 64);
  sum += __shfl_xor(sum, 2, 64);
  sum += __shfl_xor(sum, 4, 64);
  sum += __shfl_xor(sum, 8, 64);
  float mu = sum * (1.f / 64.f);
  float dx = o.x - mu, dy = o.y - mu, dz = o.z - mu, dw = o.w - mu;
  float vs = dx * dx + dy * dy + dz * dz + dw * dw;
  vs += __shfl_xor(vs, 1, 64);
  vs += __shfl_xor(vs, 2, 64);
  vs += __shfl_xor(vs, 4, 64);
  vs += __shfl_xor(vs, 8, 64);
  float rstd = rsqrtf(vs * (1.f / 64.f) + LN_EPS);
  float4 gg = *reinterpret_cast<const float4*>(ln_g + t * 4);
  float4 bb = *reinterpret_cast<const float4*>(ln_b + t * 4);
  float4 y;
  y.x = fmaxf(dx * rstd * gg.x + bb.x, 0.f);
  y.y = fmaxf(dy * rstd * gg.y + bb.y, 0.f);
  y.z = fmaxf(dz * rstd * gg.z + bb.z, 0.f);
  y.w = fmaxf(dw * rstd * gg.w + bb.w, 0.f);
  *reinterpret_cast<float4*>(h_out + (size_t)node * 64 + t * 4) = y;
}

// ---------------------------------------------------------------- launch
extern "C" void kernel_launch(void* const* d_in, const int* in_sizes, int n_in,
                              void* d_out, int out_size, void* d_ws, size_t ws_size,
                              hipStream_t stream) {
  const float* x    = (const float*)d_in[0];
  const int*   ei   = (const int*)d_in[1];
  const float* Wq0  = (const float*)d_in[2];
  const float* bq0  = (const float*)d_in[3];
  const float* Wk0  = (const float*)d_in[4];
  const float* bk0  = (const float*)d_in[5];
  const float* Wv0  = (const float*)d_in[6];
  const float* bv0  = (const float*)d_in[7];
  const float* Ws0  = (const float*)d_in[8];
  const float* bs0  = (const float*)d_in[9];
  const float* ln0g = (const float*)d_in[10];
  const float* ln0b = (const float*)d_in[11];
  const float* WqL  = (const float*)d_in[12];
  const float* bqL  = (const float*)d_in[13];
  const float* WkL  = (const float*)d_in[14];
  const float* bkL  = (const float*)d_in[15];
  const float* WvL  = (const float*)d_in[16];
  const float* bvL  = (const float*)d_in[17];
  const float* WsL  = (const float*)d_in[18];
  const float* bsL  = (const float*)d_in[19];
  const float* lnG  = (const float*)d_in[20];
  const float* lnB  = (const float*)d_in[21];

  float* h = (float*)d_out;  // running hidden state [N,64] f32

  char* ws = (char*)d_ws;
  size_t off = 0;
  float* Qf = (float*)(ws + off);                    off += (size_t)NN * 64 * 4;   // 12.8MB
  float* Sf = (float*)(ws + off);                    off += (size_t)NN * 64 * 4;   // 12.8MB
  unsigned int* KVb = (unsigned int*)(ws + off);     off += (size_t)NN * 128 * 2;  // 12.8MB
  unsigned short* ell = (unsigned short*)(ws + off); off += (size_t)NN * CAP * 2;  // 6.4MB
  int* cursor = (int*)(ws + off);                    off += (size_t)NN * 4;
  unsigned short* Wt = (unsigned short*)(ws + off);  off += (size_t)4 * 256 * 64 * 2;
  float* Bc = (float*)(ws + off);                    off += (size_t)4 * 256 * 4;

  hipMemsetAsync(cursor, 0, NN * sizeof(int), stream);
  build_ell<<<BE_T / 256, 256, 0, stream>>>(ei, cursor, ell);
  wprep<<<256, 256, 0, stream>>>(Wq0, bq0, Wk0, bk0, Wv0, bv0, Ws0, bs0,
                                 WqL, bqL, WkL, bkL, WvL, bvL, WsL, bsL, Wt, Bc);

  for (int layer = 0; layer < 4; ++layer) {
    const float* hin = (layer == 0) ? x : h;
    const float* lg = (layer == 0) ? ln0g : lnG + (size_t)(layer - 1) * 64;
    const float* lb = (layer == 0) ? ln0b : lnB + (size_t)(layer - 1) * 64;
    gemm_qkvs<<<(ROW_TILES + 3) / 4, 256, 0, stream>>>(
        hin, Wt + (size_t)layer * 16384, Bc + (size_t)layer * 256, Qf, KVb, Sf);
    edge_fused<<<(NN + 3) / 4, 256, 0, stream>>>(
        Qf, (const unsigned short*)KVb, Sf, ell, cursor, lg, lb, h, h,
        layer > 0 ? 1 : 0);
  }
}

// Round 5
// 392.534 us; speedup vs baseline: 2.6077x; 1.0795x over previous
//
#include <hip/hip_runtime.h>
#include <math.h>

#define NN 50000
#define NE 1000000
#define CAP 64
#define LN_EPS 1e-5f
#define ROW_TILES 3125    // 50000 / 16
#define GEMM_BLOCKS 782   // ceil(3125/4)
#define BE_T 250112       // ELL threads = 977 * 256 (x4 edges each)
#define ELL_BLOCKS 977

typedef __attribute__((ext_vector_type(8))) short short8;
typedef __attribute__((ext_vector_type(8))) unsigned short ushort8;
typedef __attribute__((ext_vector_type(4))) float f32x4;

__device__ __forceinline__ unsigned short f2bf(float f) {
  union { float f; unsigned u; } v; v.f = f;
  unsigned r = v.u + 0x7FFF + ((v.u >> 16) & 1);  // RNE
  return (unsigned short)(r >> 16);
}
__device__ __forceinline__ float bf2f(unsigned short b) {
  union { unsigned u; float f; } v; v.u = ((unsigned)b) << 16;
  return v.f;
}

// ---------------------------------------------------------------- weight prep
// Wt per layer: [256][64] bf16, row c = mat*64 + n, holds W[k][n] (transposed).
__global__ __launch_bounds__(256) void wprep(
    const float* __restrict__ Wq0, const float* __restrict__ bq0,
    const float* __restrict__ Wk0, const float* __restrict__ bk0,
    const float* __restrict__ Wv0, const float* __restrict__ bv0,
    const float* __restrict__ Ws0, const float* __restrict__ bs0,
    const float* __restrict__ WqL, const float* __restrict__ bqL,
    const float* __restrict__ WkL, const float* __restrict__ bkL,
    const float* __restrict__ WvL, const float* __restrict__ bvL,
    const float* __restrict__ WsL, const float* __restrict__ bsL,
    unsigned short* __restrict__ Wt, float* __restrict__ Bc) {
  int tid = blockIdx.x * 256 + threadIdx.x;
  if (tid >= 4 * 256 * 64) return;
  int lyr = tid >> 14;
  int rem = tid & 16383;
  int c = rem >> 6;   // 0..255
  int k = rem & 63;
  int m = c >> 6;
  int n = c & 63;
  const float *W, *B;
  if (lyr == 0) {
    const float* Wm[4] = {Wq0, Wk0, Wv0, Ws0};
    const float* Bm[4] = {bq0, bk0, bv0, bs0};
    W = Wm[m]; B = Bm[m];
  } else {
    const float* Wm[4] = {WqL, WkL, WvL, WsL};
    const float* Bm[4] = {bqL, bkL, bvL, bsL};
    W = Wm[m] + (size_t)(lyr - 1) * 4096;
    B = Bm[m] + (size_t)(lyr - 1) * 64;
  }
  Wt[(size_t)lyr * 16384 + (size_t)c * 64 + k] = f2bf(W[(size_t)k * 64 + n]);
  if (k == 0) Bc[lyr * 256 + c] = B[n];
}

// ---------------------------------------------------------------- MFMA QKVS GEMM (+optional fused ELL build)
// h [N,64] f32 -> Qb bf16 [N,64], KVb bf16 interleaved [N,128] (k,v pairs), Sf f32.
// Blocks >= nGemm run the ELL-build path instead (layer 0 only).
__global__ __launch_bounds__(256) void gemm_qkvs(
    const float* __restrict__ h, const unsigned short* __restrict__ Wt,
    const float* __restrict__ Bc, unsigned short* __restrict__ Qb,
    unsigned int* __restrict__ KVb, float* __restrict__ Sf,
    const int* __restrict__ ei, int* __restrict__ cursor,
    unsigned short* __restrict__ ell, int nGemm) {
  __shared__ unsigned short lw[256 * 72];  // padded stride 72
  int tid = threadIdx.x;

  if ((int)blockIdx.x >= nGemm) {
    // ---------------- ELL build path (latency-bound; overlaps gemm blocks)
    int t = (blockIdx.x - nGemm) * 256 + tid;
    int e[4]; bool v[4]; int s[4], d[4], p[4];
#pragma unroll
    for (int i = 0; i < 4; ++i) { e[i] = t + i * BE_T; v[i] = e[i] < NE; }
#pragma unroll
    for (int i = 0; i < 4; ++i) {
      if (v[i]) { s[i] = ei[e[i]]; d[i] = ei[NE + e[i]]; }
    }
#pragma unroll
    for (int i = 0; i < 4; ++i) {
      if (v[i]) p[i] = atomicAdd(&cursor[d[i]], 1);
    }
#pragma unroll
    for (int i = 0; i < 4; ++i) {
      if (v[i] && p[i] < CAP) ell[(size_t)d[i] * CAP + p[i]] = (unsigned short)s[i];
    }
    return;
  }

  // ---------------- GEMM path
#pragma unroll
  for (int it = 0; it < 8; ++it) {
    int id = it * 256 + tid;
    int row = id >> 3, cc = id & 7;
    float4 src = *reinterpret_cast<const float4*>(Wt + (size_t)row * 64 + cc * 8);
    *reinterpret_cast<float4*>(lw + (size_t)row * 72 + cc * 8) = src;
  }
  __syncthreads();

  int wave = tid >> 6, lane = tid & 63;
  int tile = blockIdx.x * 4 + wave;
  if (tile >= ROW_TILES) return;
  int lo = lane & 15, hi = lane >> 4;
  int row = tile * 16 + lo;
  const float* hrow = h + (size_t)row * 64;

  auto packA = [&](const float* p) {
    float4 x = *reinterpret_cast<const float4*>(p);
    float4 y = *reinterpret_cast<const float4*>(p + 4);
    short8 r;
    r[0] = (short)f2bf(x.x); r[1] = (short)f2bf(x.y);
    r[2] = (short)f2bf(x.z); r[3] = (short)f2bf(x.w);
    r[4] = (short)f2bf(y.x); r[5] = (short)f2bf(y.y);
    r[6] = (short)f2bf(y.z); r[7] = (short)f2bf(y.w);
    return r;
  };
  short8 a0 = packA(hrow + hi * 8);
  short8 a1 = packA(hrow + 32 + hi * 8);

  int rb = tile * 16 + hi * 4;

  auto mm = [&](int brow, float bias) {
    f32x4 acc = {bias, bias, bias, bias};
    const unsigned short* wr = lw + (size_t)brow * 72 + hi * 8;
    short8 b0 = *reinterpret_cast<const short8*>(wr);
    short8 b1 = *reinterpret_cast<const short8*>(wr + 32);
    acc = __builtin_amdgcn_mfma_f32_16x16x32_bf16(a0, b0, acc, 0, 0, 0);
    acc = __builtin_amdgcn_mfma_f32_16x16x32_bf16(a1, b1, acc, 0, 0, 0);
    return acc;
  };

  // Q (cols ct*16+lo), bf16 out
#pragma unroll
  for (int ct = 0; ct < 4; ++ct) {
    int col = ct * 16 + lo;
    f32x4 acc = mm(col, Bc[col]);
#pragma unroll
    for (int r = 0; r < 4; ++r) Qb[(size_t)(rb + r) * 64 + col] = f2bf(acc[r]);
  }
  // K+V packed
#pragma unroll
  for (int cg = 0; cg < 4; ++cg) {
    int col = cg * 16 + lo;
    f32x4 aK = mm(64 + col, Bc[64 + col]);
    f32x4 aV = mm(128 + col, Bc[128 + col]);
#pragma unroll
    for (int r = 0; r < 4; ++r) {
      unsigned int pk = (unsigned int)f2bf(aK[r]) | ((unsigned int)f2bf(aV[r]) << 16);
      KVb[(size_t)(rb + r) * 64 + col] = pk;
    }
  }
  // S (f32 — residual path, keep exact)
#pragma unroll
  for (int ct = 0; ct < 4; ++ct) {
    int col = ct * 16 + lo;
    f32x4 acc = mm(192 + col, Bc[192 + col]);
#pragma unroll
    for (int r = 0; r < 4; ++r) Sf[(size_t)(rb + r) * 64 + col] = acc[r];
  }
}

// ---------------------------------------------------------------- fused edge+softmax+LN+relu
// one wave per node; lane = (g = edge slot 0..3) x (t = dim quarter 0..15)
// depth-2 register prefetch of KV gathers
__global__ __launch_bounds__(256) void edge_fused(
    const unsigned short* __restrict__ Qb, const unsigned short* __restrict__ KVb,
    const float* __restrict__ Sf,
    const unsigned short* __restrict__ ell, const int* __restrict__ cursor,
    const float* __restrict__ ln_g, const float* __restrict__ ln_b,
    const float* __restrict__ h_res, float* __restrict__ h_out, int use_res) {
  int node = blockIdx.x * 4 + (threadIdx.x >> 6);
  if (node >= NN) return;
  int lane = threadIdx.x & 63;
  int g = lane >> 4, t = lane & 15;

  int deg = cursor[node];
  if (deg > CAP) deg = CAP;
  const unsigned short* lst = ell + (size_t)node * CAP;

  ushort4 qv = *reinterpret_cast<const ushort4*>(Qb + (size_t)node * 64 + t * 4);
  float q0 = bf2f(qv.x), q1 = bf2f(qv.y), q2 = bf2f(qv.z), q3 = bf2f(qv.w);

  int passes = (deg + 3) >> 2;

  auto ldkv = [&](int p) {
    int slot = p * 4 + g;
    int src = (slot < deg) ? (int)lst[slot] : 0;  // masked load; slot<deg => in-bounds
    return *reinterpret_cast<const ushort8*>(KVb + (size_t)src * 128 + t * 8);
  };

  float4 acc = {0.f, 0.f, 0.f, 0.f};
  float ssum = 0.f;
  ushort8 b0 = ldkv(0);
  ushort8 b1 = ldkv(1);
  for (int p = 0; p < passes; ++p) {
    ushort8 b2 = ldkv(p + 2);  // in flight while we reduce b0
    bool valid = (p * 4 + g) < deg;
    float dp = q0 * bf2f(b0[0]) + q1 * bf2f(b0[2]) +
               q2 * bf2f(b0[4]) + q3 * bf2f(b0[6]);
    dp += __shfl_xor(dp, 1, 64);
    dp += __shfl_xor(dp, 2, 64);
    dp += __shfl_xor(dp, 4, 64);
    dp += __shfl_xor(dp, 8, 64);
    // softmax is shift-invariant; logits O(1) -> no max subtraction needed
    float w = valid ? __expf(dp * 0.125f) : 0.f;
    ssum += w;
    acc.x = fmaf(w, bf2f(b0[1]), acc.x);
    acc.y = fmaf(w, bf2f(b0[3]), acc.y);
    acc.z = fmaf(w, bf2f(b0[5]), acc.z);
    acc.w = fmaf(w, bf2f(b0[7]), acc.w);
    b0 = b1; b1 = b2;
  }
  // combine the 4 edge groups
#pragma unroll
  for (int off = 16; off <= 32; off <<= 1) {
    acc.x += __shfl_xor(acc.x, off, 64);
    acc.y += __shfl_xor(acc.y, off, 64);
    acc.z += __shfl_xor(acc.z, off, 64);
    acc.w += __shfl_xor(acc.w, off, 64);
    ssum  += __shfl_xor(ssum, off, 64);
  }
  float inv = (ssum > 0.f) ? (1.f / ssum) : 0.f;

  float4 s4 = *reinterpret_cast<const float4*>(Sf + (size_t)node * 64 + t * 4);
  float4 o;
  o.x = acc.x * inv + s4.x;
  o.y = acc.y * inv + s4.y;
  o.z = acc.z * inv + s4.z;
  o.w = acc.w * inv + s4.w;
  if (use_res) {
    float4 r4 = *reinterpret_cast<const float4*>(h_res + (size_t)node * 64 + t * 4);
    o.x += r4.x; o.y += r4.y; o.z += r4.z; o.w += r4.w;
  }

  // LayerNorm over 64 dims (16 lanes x float4; groups hold identical copies)
  float sum = o.x + o.y + o.z + o.w;
  sum += __shfl_xor(sum, 1, 64);
  sum += __shfl_xor(sum, 2, 64);
  sum += __shfl_xor(sum, 4, 64);
  sum += __shfl_xor(sum, 8, 64);
  float mu = sum * (1.f / 64.f);
  float dx = o.x - mu, dy = o.y - mu, dz = o.z - mu, dw = o.w - mu;
  float vs = dx * dx + dy * dy + dz * dz + dw * dw;
  vs += __shfl_xor(vs, 1, 64);
  vs += __shfl_xor(vs, 2, 64);
  vs += __shfl_xor(vs, 4, 64);
  vs += __shfl_xor(vs, 8, 64);
  float rstd = rsqrtf(vs * (1.f / 64.f) + LN_EPS);
  float4 gg = *reinterpret_cast<const float4*>(ln_g + t * 4);
  float4 bb = *reinterpret_cast<const float4*>(ln_b + t * 4);
  float4 y;
  y.x = fmaxf(dx * rstd * gg.x + bb.x, 0.f);
  y.y = fmaxf(dy * rstd * gg.y + bb.y, 0.f);
  y.z = fmaxf(dz * rstd * gg.z + bb.z, 0.f);
  y.w = fmaxf(dw * rstd * gg.w + bb.w, 0.f);
  *reinterpret_cast<float4*>(h_out + (size_t)node * 64 + t * 4) = y;
}

// ---------------------------------------------------------------- launch
extern "C" void kernel_launch(void* const* d_in, const int* in_sizes, int n_in,
                              void* d_out, int out_size, void* d_ws, size_t ws_size,
                              hipStream_t stream) {
  const float* x    = (const float*)d_in[0];
  const int*   ei   = (const int*)d_in[1];
  const float* Wq0  = (const float*)d_in[2];
  const float* bq0  = (const float*)d_in[3];
  const float* Wk0  = (const float*)d_in[4];
  const float* bk0  = (const float*)d_in[5];
  const float* Wv0  = (const float*)d_in[6];
  const float* bv0  = (const float*)d_in[7];
  const float* Ws0  = (const float*)d_in[8];
  const float* bs0  = (const float*)d_in[9];
  const float* ln0g = (const float*)d_in[10];
  const float* ln0b = (const float*)d_in[11];
  const float* WqL  = (const float*)d_in[12];
  const float* bqL  = (const float*)d_in[13];
  const float* WkL  = (const float*)d_in[14];
  const float* bkL  = (const float*)d_in[15];
  const float* WvL  = (const float*)d_in[16];
  const float* bvL  = (const float*)d_in[17];
  const float* WsL  = (const float*)d_in[18];
  const float* bsL  = (const float*)d_in[19];
  const float* lnG  = (const float*)d_in[20];
  const float* lnB  = (const float*)d_in[21];

  float* h = (float*)d_out;  // running hidden state [N,64] f32

  char* ws = (char*)d_ws;
  size_t off = 0;
  unsigned short* Qb = (unsigned short*)(ws + off);  off += (size_t)NN * 64 * 2;   // 6.4MB
  float* Sf = (float*)(ws + off);                    off += (size_t)NN * 64 * 4;   // 12.8MB
  unsigned int* KVb = (unsigned int*)(ws + off);     off += (size_t)NN * 128 * 2;  // 12.8MB
  unsigned short* ell = (unsigned short*)(ws + off); off += (size_t)NN * CAP * 2;  // 6.4MB
  int* cursor = (int*)(ws + off);                    off += (size_t)NN * 4;
  unsigned short* Wt = (unsigned short*)(ws + off);  off += (size_t)4 * 256 * 64 * 2;
  float* Bc = (float*)(ws + off);                    off += (size_t)4 * 256 * 4;

  hipMemsetAsync(cursor, 0, NN * sizeof(int), stream);
  wprep<<<256, 256, 0, stream>>>(Wq0, bq0, Wk0, bk0, Wv0, bv0, Ws0, bs0,
                                 WqL, bqL, WkL, bkL, WvL, bvL, WsL, bsL, Wt, Bc);

  for (int layer = 0; layer < 4; ++layer) {
    const float* hin = (layer == 0) ? x : h;
    const float* lg = (layer == 0) ? ln0g : lnG + (size_t)(layer - 1) * 64;
    const float* lb = (layer == 0) ? ln0b : lnB + (size_t)(layer - 1) * 64;
    int extra = (layer == 0) ? ELL_BLOCKS : 0;  // fuse ELL build under layer-0 GEMM
    gemm_qkvs<<<GEMM_BLOCKS + extra, 256, 0, stream>>>(
        hin, Wt + (size_t)layer * 16384, Bc + (size_t)layer * 256,
        Qb, KVb, Sf, ei, cursor, ell, GEMM_BLOCKS);
    edge_fused<<<(NN + 3) / 4, 256, 0, stream>>>(
        Qb, (const unsigned short*)KVb, Sf, ell, cursor, lg, lb, h, h,
        layer > 0 ? 1 : 0);
  }
}